// Round 8
// baseline (97.562 us; speedup 1.0000x reference)
//
#include <hip/hip_runtime.h>
#include <math.h>

typedef float f4_t __attribute__((ext_vector_type(4)));

#define NTERM 22           // Taylor powers T_0..T_21 of Z=-iH (||Z||<=5 -> err ~1e-8)
#define TROW  9            // padded row stride (float2) inside one T matrix
#define TMAT  (TROW * 8)   // float2 per stored matrix

__device__ __forceinline__ double rdin(const void* p, int idx, bool isdbl) {
  return isdbl ? ((const double*)p)[idx] : (double)((const float*)p)[idx];
}

__device__ __forceinline__ bool detect_dbl(const void* xv) {
  // f64 data reinterpreted as f32 words shows wild exponents in the low
  // (mantissa) words; true f32 N(0,1) never exceeds 1e6. 64 words => P(miss)~2e-8.
  const float* xq = (const float*)xv;
  bool isdbl = false;
  for (int j = 0; j < 64; ++j) {
    float a = fabsf(xq[j]);
    if (!(a < 1e6f)) isdbl = true;
  }
  return isdbl;
}

// ---------------------------------------------------------------------------
// Single fused kernel. Grid = 4*B workgroups x 256 threads; wg (i, jblk)
// owns sample i's I_k slice j=jblk (64 KB) and (jblk==0) its I_b (16 KB).
//
// R7->R8 single lever: every store wave-instruction now writes ONE fully
// contiguous 1KB run (was 4 x 256B chunks at 1KB stride).  I_k rows for
// fixed (j,k) and l=0..3 are 256 consecutive floats = 4 scaled copies of
// M-row k, so each wave takes a uniform k (= it*4 + wv) and lane tl covers
// floats 4*tl..4*tl+3 (l = tl>>4, col = (tl&15)*4).  M values recomputed
// per lane-group from gk_t/hk_t (redundant FMA, overlaps the drain).
// I_b likewise: addr = r*1024 + 4*t is contiguous per wave.
//
// Solve (phases 1-6) unchanged: Taylor/Krylov + exact Frechet contraction,
// solver wave = wave jblk so co-resident wgs solve on different SIMDs.
// ---------------------------------------------------------------------------
__global__ __launch_bounds__(256) void fi_all(
    const void* __restrict__ xv,
    const void* __restrict__ kv,
    const void* __restrict__ bv,
    float* __restrict__ out, int Bn)
{
  const int wg   = blockIdx.x;
  const int i    = wg >> 2;
  const int jblk = wg & 3;
  const int t    = threadIdx.x;        // 0..255
  const int wv   = t >> 6;             // wave id 0..3
  const int tl   = t & 63;             // lane within wave
  const bool solver = (wv == jblk);    // each wg solves on a DIFFERENT SIMD

  __shared__ float  pw[64];
  __shared__ float2 Zl[8][8];
  __shared__ float  invfact[48];
  __shared__ float2 Tall[NTERM * TMAT];
  __shared__ float2 Rl[NTERM][8];
  __shared__ float2 Ql[8][8][8];
  __shared__ float  ampre[8], ampim[8], invPs[8];
  __shared__ float  gk_t[8][64];       // g transposed: gk_t[p][k]
  __shared__ float  hk_t[8][68];       // h = g/P transposed, padded

  const bool isdbl = detect_dbl(xv);

  // ---- phase 1: pw (solver wave) | 1/n! table (next wave, fast rcp) -------
  if (solver) {
    float acc = (float)rdin(bv, tl, isdbl);
    #pragma unroll
    for (int j = 0; j < 4; ++j)
      acc += (float)rdin(xv, i*4 + j, isdbl) * (float)rdin(kv, j*64 + tl, isdbl);
    pw[tl] = acc;
  } else if (wv == ((jblk + 1) & 3) && tl < 48) {
    int n = tl;
    float f = 1.0f;
    for (int u = 2; u <= n; ++u) f *= __builtin_amdgcn_rcpf((float)u);
    invfact[n] = f;
  }
  __syncthreads();

  // ---- phase 2: build Z = -iH from analytic Pauli strings (solver wave) ---
  if (solver) {
    int r = tl >> 3, c = tl & 7;
    int m = r ^ c;
    float hre = 0.0f, him = 0.0f;
    for (int u = 0; u < 8; ++u) {
      int k = 0;
      float pr = 1.0f, pim = 0.0f;
      #pragma unroll
      for (int q = 0; q < 3; ++q) {
        int bit = 2 - q;
        int f  = (m >> bit) & 1;
        int ch = (u >> bit) & 1;
        int rb = (r >> bit) & 1;
        int d  = f ? (ch ? 2 : 1) : (ch ? 3 : 0);  // I=0,X=1,Y=2,Z=3
        k = (k << 2) | d;
        if (d == 2) {
          float nr = rb ? -pim : pim;
          float ni = rb ?  pr  : -pr;
          pr = nr; pim = ni;
        } else if (d == 3 && rb) { pr = -pr; pim = -pim; }
      }
      float w = pw[k];
      hre += w * pr; him += w * pim;
    }
    Zl[r][c] = make_float2(him, -hre);   // -i*(hre + i*him)
  }
  __syncthreads();

  // ---- phase 3: Krylov chain T_j = Z^j, register-resident (solver wave) ---
  if (solver) {
    const int r = tl >> 3, c = tl & 7;
    float2 Zrow[8];
    #pragma unroll
    for (int u = 0; u < 8; ++u) Zrow[u] = Zl[r][u];
    float Tre = (r == c) ? 1.0f : 0.0f;
    float Tim = 0.0f;
    Tall[r*TROW + c] = make_float2(Tre, Tim);
    #pragma unroll
    for (int j = 1; j < NTERM; ++j) {
      float cr[8], ci[8];
      #pragma unroll
      for (int u = 0; u < 8; ++u) {
        int srcl = (((u << 3) | c) << 2);            // byte addr = lane*4
        cr[u] = __int_as_float(__builtin_amdgcn_ds_bpermute(srcl, __float_as_int(Tre)));
        ci[u] = __int_as_float(__builtin_amdgcn_ds_bpermute(srcl, __float_as_int(Tim)));
      }
      float nr = 0.0f, ni = 0.0f;
      #pragma unroll
      for (int u = 0; u < 8; ++u) {
        nr += Zrow[u].x*cr[u] - Zrow[u].y*ci[u];
        ni += Zrow[u].x*ci[u] + Zrow[u].y*cr[u];
      }
      Tre = nr; Tim = ni;
      Tall[j*TMAT + r*TROW + c] = make_float2(nr, ni);
    }
  }
  __syncthreads();

  // ---- phase 4: R_l[b] = sum_j A_j[b]/(j+l+1)!  and  psi, 1/P -------------
  if (t < NTERM * 8) {
    const int l = t >> 3, b = t & 7;
    float sr = 0.0f, si = 0.0f;
    for (int j = 0; j < NTERM; ++j) {
      float cf = invfact[j + l + 1];
      float2 a = Tall[j*TMAT + b*TROW];          // A_j[b] = T_j[b][0]
      sr += cf * a.x; si += cf * a.y;
    }
    Rl[l][b] = make_float2(sr, si);
  }
  if (t >= 192 && t < 200) {                      // psi on wave3 (spread load)
    const int b = t - 192;
    float ar = 0.0f, ai = 0.0f;
    for (int j = 0; j < NTERM; ++j) {
      float cf = invfact[j];
      float2 a = Tall[j*TMAT + b*TROW];
      ar += cf * a.x; ai += cf * a.y;
    }
    ampre[b] = ar; ampim[b] = ai;
    float P = ar*ar + ai*ai;
    invPs[b] = 1.0f / fmaxf(P, 1e-30f);
  }
  __syncthreads();

  // ---- phase 5: Q[p][a][b] = sum_l T_l[p,a] * R_l[b]  (all 256 threads) ---
  {
    const int p  = t >> 5;
    const int a  = (t >> 2) & 7;
    const int b0 = (t & 3) << 1;
    float q0r = 0.f, q0i = 0.f, q1r = 0.f, q1i = 0.f;
    for (int l = 0; l < NTERM; ++l) {
      float2 T  = Tall[l*TMAT + p*TROW + a];
      float2 r0 = Rl[l][b0];
      float2 r1 = Rl[l][b0+1];
      q0r += T.x*r0.x - T.y*r0.y;  q0i += T.x*r0.y + T.y*r0.x;
      q1r += T.x*r1.x - T.y*r1.y;  q1i += T.x*r1.y + T.y*r1.x;
    }
    Ql[p][a][b0]   = make_float2(q0r, q0i);
    Ql[p][a][b0+1] = make_float2(q1r, q1i);
  }
  __syncthreads();

  // ---- phase 6: Jacobian, all 256 threads (k = t&63, 2 p's per thread) ----
  {
    const int k  = t & 63;
    const int pg = t >> 6;               // p in {2pg, 2pg+1}
    const int p0 = pg << 1, p1 = p0 + 1;
    const int d0 = (k >> 4) & 3, d1 = (k >> 2) & 3, d2 = k & 3;
    const int m = ((((d0 == 1) | (d0 == 2)) ? 1 : 0) << 2)
                | ((((d1 == 1) | (d1 == 2)) ? 1 : 0) << 1)
                |  (((d2 == 1) | (d2 == 2)) ? 1 : 0);
    float S0r = 0.f, S0i = 0.f, S1r = 0.f, S1i = 0.f;
    #pragma unroll
    for (int a = 0; a < 8; ++a) {
      float pr = 1.0f, pim = 0.0f;               // phi_k(a) in {+-1, +-i}
      const int dd[3] = {d0, d1, d2};
      #pragma unroll
      for (int q = 0; q < 3; ++q) {
        int rb = (a >> (2 - q)) & 1;
        int d = dd[q];
        if (d == 2) {
          float nr = rb ? -pim : pim;
          float ni = rb ?  pr  : -pr;
          pr = nr; pim = ni;
        } else if (d == 3 && rb) { pr = -pr; pim = -pim; }
      }
      const int b = a ^ m;
      float2 qa = Ql[p0][a][b];
      float2 qb = Ql[p1][a][b];
      S0r += pr*qa.x - pim*qa.y;  S0i += pr*qa.y + pim*qa.x;
      S1r += pr*qb.x - pim*qb.y;  S1i += pr*qb.y + pim*qb.x;
    }
    // dpsi = -i*S ;  g = 2 Re(conj(psi)*dpsi) = 2(psi_re*Si - psi_im*Sr)
    float g0 = 2.0f * (ampre[p0]*S0i - ampim[p0]*S0r);
    float g1 = 2.0f * (ampre[p1]*S1i - ampim[p1]*S1r);
    gk_t[p0][k] = g0;  hk_t[p0][k] = g0 * invPs[p0];
    gk_t[p1][k] = g1;  hk_t[p1][k] = g1 * invPs[p1];
  }

  // per-thread scale x[jblk]*x[l] (l = tl>>4), loaded before the barrier
  float sc_l;
  {
    float xj = (float)rdin(xv, i*4 + jblk, isdbl);
    sc_l = xj * (float)rdin(xv, i*4 + (tl >> 4), isdbl);
  }
  __syncthreads();

  // ---- phase 7: contiguous-1KB-per-wave-instruction stores ----------------
  // hoisted h fragments: column block (tl&15)*4, fixed per thread
  const int m4 = (tl & 15) << 2;
  f4_t hv[8];
  #pragma unroll
  for (int p = 0; p < 8; ++p) hv[p] = *(const f4_t*)&hk_t[p][m4];

  // I_k: wave-uniform row k = it*4 + wv; lane tl writes floats 4tl..4tl+3
  // of the 256-float run I_k[i, jblk, k, 0..3, 0..63]  (fully contiguous).
  {
    float* okj = out + (size_t)i * 65536 + (size_t)jblk * 16384;
    #pragma unroll
    for (int it = 0; it < 16; ++it) {
      const int k = it*4 + wv;
      f4_t acc = {0.f, 0.f, 0.f, 0.f};
      #pragma unroll
      for (int p = 0; p < 8; ++p) {
        float gv = gk_t[p][k];           // wave-uniform broadcast read
        acc.x += gv*hv[p].x; acc.y += gv*hv[p].y;
        acc.z += gv*hv[p].z; acc.w += gv*hv[p].w;
      }
      f4_t vv = {sc_l*acc.x, sc_l*acc.y, sc_l*acc.z, sc_l*acc.w};
      *(f4_t*)(okj + (size_t)k*256 + (size_t)tl*4) = vv;
    }
  }

  // I_b (jblk==0 only): addr = r*1024 + 4t -> contiguous 1KB per wave-instr
  if (jblk == 0) {
    float* ob = out + (size_t)Bn * 65536 + (size_t)i * 4096;
    #pragma unroll
    for (int r = 0; r < 4; ++r) {
      const int k = r*16 + (t >> 4);     // (t>>4)*64 + (t&15)*4 == 4t
      f4_t acc = {0.f, 0.f, 0.f, 0.f};
      #pragma unroll
      for (int p = 0; p < 8; ++p) {
        float gv = gk_t[p][k];
        acc.x += gv*hv[p].x; acc.y += gv*hv[p].y;
        acc.z += gv*hv[p].z; acc.w += gv*hv[p].w;
      }
      *(f4_t*)(ob + (size_t)r*1024 + (size_t)t*4) = acc;
    }
  }
}

extern "C" void kernel_launch(void* const* d_in, const int* in_sizes, int n_in,
                              void* d_out, int out_size, void* d_ws, size_t ws_size,
                              hipStream_t stream) {
  (void)n_in; (void)d_ws; (void)ws_size; (void)out_size;
  int Bn = in_sizes[0] / 4;   // 256
  fi_all<<<Bn * 4, 256, 0, stream>>>(d_in[0], d_in[1], d_in[2], (float*)d_out, Bn);
}

// Round 9
// 96.304 us; speedup vs baseline: 1.0131x; 1.0131x over previous
//
#include <hip/hip_runtime.h>
#include <math.h>

typedef float f4_t __attribute__((ext_vector_type(4)));

#define NTERM 22           // Taylor powers T_0..T_21 of Z=-iH (||Z||<=5 -> err ~1e-8)
#define TROW  9            // padded row stride (float2) inside one T matrix
#define TMAT  (TROW * 8)   // float2 per stored matrix

__device__ __forceinline__ double rdin(const void* p, int idx, bool isdbl) {
  return isdbl ? ((const double*)p)[idx] : (double)((const float*)p)[idx];
}

// ---------------------------------------------------------------------------
// Single fused kernel. Grid = 4*B workgroups x 256 threads; wg (i, jblk)
// owns sample i's I_k slice j=jblk (64 KB) and (jblk==0) its I_b (16 KB).
//
// R8->R9 trim pass (cycle-budget audit: stores ~11.5us/CU are irreducible;
// the addressable slack was redundant preamble + LDS-read inefficiency):
//  1. detect_dbl: was 64 serial wave-uniform loads PER THREAD (~3-5us/CU,
//     present since R0, never ablated). Now wave-parallel: lane tl checks
//     word tl, one coalesced load + 64-bit __ballot.
//  2. gk stored k-major (gk_km[64][8]): phase 7's per-k gather = 2 broadcast
//     ds_read_b128 instead of 8 ds_read_b32 (4x fewer LDS instrs in the
//     hottest loop).
//  3. phase-5 Rl pair read as one aligned 16B load.
// Solve math unchanged (Taylor/Krylov + exact Frechet contraction); solver
// wave = wave jblk so co-resident wgs solve on different SIMDs (R6); plain
// contiguous dwordx4 stores (R7/R8).
// ---------------------------------------------------------------------------
__global__ __launch_bounds__(256) void fi_all(
    const void* __restrict__ xv,
    const void* __restrict__ kv,
    const void* __restrict__ bv,
    float* __restrict__ out, int Bn)
{
  const int wg   = blockIdx.x;
  const int i    = wg >> 2;
  const int jblk = wg & 3;
  const int t    = threadIdx.x;        // 0..255
  const int wv   = t >> 6;             // wave id 0..3
  const int tl   = t & 63;             // lane within wave
  const bool solver = (wv == jblk);    // each wg solves on a DIFFERENT SIMD

  __shared__ float  pw[64];
  __shared__ float2 Zl[8][8];
  __shared__ float  invfact[48];
  __shared__ float2 Tall[NTERM * TMAT];
  __shared__ float2 Rl[NTERM][8];
  __shared__ float2 Ql[8][8][8];
  __shared__ float  ampre[8], ampim[8], invPs[8];
  __shared__ __align__(16) float gk_km[64][8];  // g, k-major rows (b128-readable)
  __shared__ __align__(16) float hk_t[8][68];   // h = g/P, p-major, padded

  // ---- wave-parallel dtype sniff: lane tl checks word tl ------------------
  // f64 data reinterpreted as f32 words shows wild exponents in the low
  // (mantissa) words; true f32 N(0,1) never exceeds 1e6. 64 words checked.
  const bool isdbl =
      (__ballot(!(fabsf(((const float*)xv)[tl]) < 1e6f)) != 0ull);

  // ---- phase 1: pw (solver wave) | 1/n! table (next wave, fast rcp) -------
  if (solver) {
    float acc = (float)rdin(bv, tl, isdbl);
    #pragma unroll
    for (int j = 0; j < 4; ++j)
      acc += (float)rdin(xv, i*4 + j, isdbl) * (float)rdin(kv, j*64 + tl, isdbl);
    pw[tl] = acc;
  } else if (wv == ((jblk + 1) & 3) && tl < 48) {
    int n = tl;
    float f = 1.0f;
    for (int u = 2; u <= n; ++u) f *= __builtin_amdgcn_rcpf((float)u);
    invfact[n] = f;
  }
  __syncthreads();

  // ---- phase 2: build Z = -iH from analytic Pauli strings (solver wave) ---
  if (solver) {
    int r = tl >> 3, c = tl & 7;
    int m = r ^ c;
    float hre = 0.0f, him = 0.0f;
    for (int u = 0; u < 8; ++u) {
      int k = 0;
      float pr = 1.0f, pim = 0.0f;
      #pragma unroll
      for (int q = 0; q < 3; ++q) {
        int bit = 2 - q;
        int f  = (m >> bit) & 1;
        int ch = (u >> bit) & 1;
        int rb = (r >> bit) & 1;
        int d  = f ? (ch ? 2 : 1) : (ch ? 3 : 0);  // I=0,X=1,Y=2,Z=3
        k = (k << 2) | d;
        if (d == 2) {
          float nr = rb ? -pim : pim;
          float ni = rb ?  pr  : -pr;
          pr = nr; pim = ni;
        } else if (d == 3 && rb) { pr = -pr; pim = -pim; }
      }
      float w = pw[k];
      hre += w * pr; him += w * pim;
    }
    Zl[r][c] = make_float2(him, -hre);   // -i*(hre + i*him)
  }
  __syncthreads();

  // ---- phase 3: Krylov chain T_j = Z^j, register-resident (solver wave) ---
  if (solver) {
    const int r = tl >> 3, c = tl & 7;
    float2 Zrow[8];
    #pragma unroll
    for (int u = 0; u < 8; ++u) Zrow[u] = Zl[r][u];
    float Tre = (r == c) ? 1.0f : 0.0f;
    float Tim = 0.0f;
    Tall[r*TROW + c] = make_float2(Tre, Tim);
    #pragma unroll
    for (int j = 1; j < NTERM; ++j) {
      float cr[8], ci[8];
      #pragma unroll
      for (int u = 0; u < 8; ++u) {
        int srcl = (((u << 3) | c) << 2);            // byte addr = lane*4
        cr[u] = __int_as_float(__builtin_amdgcn_ds_bpermute(srcl, __float_as_int(Tre)));
        ci[u] = __int_as_float(__builtin_amdgcn_ds_bpermute(srcl, __float_as_int(Tim)));
      }
      float nr = 0.0f, ni = 0.0f;
      #pragma unroll
      for (int u = 0; u < 8; ++u) {
        nr += Zrow[u].x*cr[u] - Zrow[u].y*ci[u];
        ni += Zrow[u].x*ci[u] + Zrow[u].y*cr[u];
      }
      Tre = nr; Tim = ni;
      Tall[j*TMAT + r*TROW + c] = make_float2(nr, ni);
    }
  }
  __syncthreads();

  // ---- phase 4: R_l[b] = sum_j A_j[b]/(j+l+1)!  and  psi, 1/P -------------
  if (t < NTERM * 8) {
    const int l = t >> 3, b = t & 7;
    float sr = 0.0f, si = 0.0f;
    for (int j = 0; j < NTERM; ++j) {
      float cf = invfact[j + l + 1];
      float2 a = Tall[j*TMAT + b*TROW];          // A_j[b] = T_j[b][0]
      sr += cf * a.x; si += cf * a.y;
    }
    Rl[l][b] = make_float2(sr, si);
  }
  if (t >= 192 && t < 200) {                      // psi on wave3 (spread load)
    const int b = t - 192;
    float ar = 0.0f, ai = 0.0f;
    for (int j = 0; j < NTERM; ++j) {
      float cf = invfact[j];
      float2 a = Tall[j*TMAT + b*TROW];
      ar += cf * a.x; ai += cf * a.y;
    }
    ampre[b] = ar; ampim[b] = ai;
    float P = ar*ar + ai*ai;
    invPs[b] = 1.0f / fmaxf(P, 1e-30f);
  }
  __syncthreads();

  // ---- phase 5: Q[p][a][b] = sum_l T_l[p,a] * R_l[b]  (all 256 threads) ---
  {
    const int p  = t >> 5;
    const int a  = (t >> 2) & 7;
    const int b0 = (t & 3) << 1;                 // even -> 16B-aligned Rl pair
    float q0r = 0.f, q0i = 0.f, q1r = 0.f, q1i = 0.f;
    for (int l = 0; l < NTERM; ++l) {
      float2 T  = Tall[l*TMAT + p*TROW + a];
      f4_t  rp  = *(const f4_t*)&Rl[l][b0];      // {r0.re, r0.im, r1.re, r1.im}
      q0r += T.x*rp.x - T.y*rp.y;  q0i += T.x*rp.y + T.y*rp.x;
      q1r += T.x*rp.z - T.y*rp.w;  q1i += T.x*rp.w + T.y*rp.z;
    }
    Ql[p][a][b0]   = make_float2(q0r, q0i);
    Ql[p][a][b0+1] = make_float2(q1r, q1i);
  }
  __syncthreads();

  // ---- phase 6: Jacobian, all 256 threads (k = t&63, 2 p's per thread) ----
  {
    const int k  = t & 63;
    const int pg = t >> 6;               // p in {2pg, 2pg+1}
    const int p0 = pg << 1, p1 = p0 + 1;
    const int d0 = (k >> 4) & 3, d1 = (k >> 2) & 3, d2 = k & 3;
    const int m = ((((d0 == 1) | (d0 == 2)) ? 1 : 0) << 2)
                | ((((d1 == 1) | (d1 == 2)) ? 1 : 0) << 1)
                |  (((d2 == 1) | (d2 == 2)) ? 1 : 0);
    float S0r = 0.f, S0i = 0.f, S1r = 0.f, S1i = 0.f;
    #pragma unroll
    for (int a = 0; a < 8; ++a) {
      float pr = 1.0f, pim = 0.0f;               // phi_k(a) in {+-1, +-i}
      const int dd[3] = {d0, d1, d2};
      #pragma unroll
      for (int q = 0; q < 3; ++q) {
        int rb = (a >> (2 - q)) & 1;
        int d = dd[q];
        if (d == 2) {
          float nr = rb ? -pim : pim;
          float ni = rb ?  pr  : -pr;
          pr = nr; pim = ni;
        } else if (d == 3 && rb) { pr = -pr; pim = -pim; }
      }
      const int b = a ^ m;
      float2 qa = Ql[p0][a][b];
      float2 qb = Ql[p1][a][b];
      S0r += pr*qa.x - pim*qa.y;  S0i += pr*qa.y + pim*qa.x;
      S1r += pr*qb.x - pim*qb.y;  S1i += pr*qb.y + pim*qb.x;
    }
    // dpsi = -i*S ;  g = 2 Re(conj(psi)*dpsi) = 2(psi_re*Si - psi_im*Sr)
    float g0 = 2.0f * (ampre[p0]*S0i - ampim[p0]*S0r);
    float g1 = 2.0f * (ampre[p1]*S1i - ampim[p1]*S1r);
    *(float2*)&gk_km[k][p0] = make_float2(g0, g1);   // k-major row
    hk_t[p0][k] = g0 * invPs[p0];
    hk_t[p1][k] = g1 * invPs[p1];
  }

  // per-thread scale x[jblk]*x[l] (l = tl>>4), loaded before the barrier
  float sc_l;
  {
    float xj = (float)rdin(xv, i*4 + jblk, isdbl);
    sc_l = xj * (float)rdin(xv, i*4 + (tl >> 4), isdbl);
  }
  __syncthreads();

  // ---- phase 7: contiguous-1KB-per-wave-instruction stores ----------------
  // hoisted h fragments: column block (tl&15)*4, fixed per thread
  const int m4 = (tl & 15) << 2;
  f4_t hv[8];
  #pragma unroll
  for (int p = 0; p < 8; ++p) hv[p] = *(const f4_t*)&hk_t[p][m4];

  // I_k: wave-uniform row k = it*4 + wv; lane tl writes floats 4tl..4tl+3
  // of the 256-float run I_k[i, jblk, k, 0..3, 0..63]. Per-k g row is two
  // broadcast ds_read_b128 (k-major layout).
  {
    float* okj = out + (size_t)i * 65536 + (size_t)jblk * 16384;
    #pragma unroll
    for (int it = 0; it < 16; ++it) {
      const int k = it*4 + wv;
      const f4_t ga = *(const f4_t*)&gk_km[k][0];
      const f4_t gb = *(const f4_t*)&gk_km[k][4];
      f4_t acc = ga.x*hv[0] + ga.y*hv[1] + ga.z*hv[2] + ga.w*hv[3]
               + gb.x*hv[4] + gb.y*hv[5] + gb.z*hv[6] + gb.w*hv[7];
      f4_t vv = sc_l * acc;
      *(f4_t*)(okj + (size_t)k*256 + (size_t)tl*4) = vv;
    }
  }

  // I_b (jblk==0 only): addr = r*1024 + 4t -> contiguous 1KB per wave-instr
  if (jblk == 0) {
    float* ob = out + (size_t)Bn * 65536 + (size_t)i * 4096;
    #pragma unroll
    for (int r = 0; r < 4; ++r) {
      const int k = r*16 + (t >> 4);     // (t>>4)*64 + (t&15)*4 == 4t
      const f4_t ga = *(const f4_t*)&gk_km[k][0];
      const f4_t gb = *(const f4_t*)&gk_km[k][4];
      f4_t acc = ga.x*hv[0] + ga.y*hv[1] + ga.z*hv[2] + ga.w*hv[3]
               + gb.x*hv[4] + gb.y*hv[5] + gb.z*hv[6] + gb.w*hv[7];
      *(f4_t*)(ob + (size_t)r*1024 + (size_t)t*4) = acc;
    }
  }
}

extern "C" void kernel_launch(void* const* d_in, const int* in_sizes, int n_in,
                              void* d_out, int out_size, void* d_ws, size_t ws_size,
                              hipStream_t stream) {
  (void)n_in; (void)d_ws; (void)ws_size; (void)out_size;
  int Bn = in_sizes[0] / 4;   // 256
  fi_all<<<Bn * 4, 256, 0, stream>>>(d_in[0], d_in[1], d_in[2], (float*)d_out, Bn);
}

// Round 10
// 94.127 us; speedup vs baseline: 1.0365x; 1.0231x over previous
//
#include <hip/hip_runtime.h>
#include <math.h>

typedef float f4_t __attribute__((ext_vector_type(4)));

#define NTERM 20           // Taylor powers T_0..T_19 of Z=-iH (||Z||<=4 -> err ~5e-7)
#define TROW  9            // padded row stride (float2) inside one T matrix
#define TMAT  (TROW * 8)   // float2 per stored matrix

__device__ __forceinline__ double rdin(const void* p, int idx, bool isdbl) {
  return isdbl ? ((const double*)p)[idx] : (double)((const float*)p)[idx];
}

// ---------------------------------------------------------------------------
// Single fused kernel. Grid = 2*B workgroups x 256 threads; wg (i, jblk)
// owns sample i's I_k slices j = {2*jblk, 2*jblk+1} (128 KB) and (jblk==0)
// its I_b (16 KB).
//
// R9->R10 lever: halve the front redundancy.  Model (from R7-R9 nulls):
// phase-7 compute is HIDDEN under the HBM-write backpressure drain (shaving
// its LDS instrs was null), the drain itself is byte-bound (~10 B/cy/CU;
// shape/NT/occupancy all null), so the exposed cost is the 4x-duplicated
// front (phases 1-6, ~4us/wg, all four wgs of a sample computing the same
// solve).  2 wgs/sample halves that; 8 waves/CU still >> the ~3 waves
// fillBuffer needs to saturate writes.  Riders: NTERM 22->20, solver wave
// = 2*(i&1)+jblk to keep co-resident solves on distinct SIMDs.
//
// Solve math unchanged (Taylor/Krylov + exact Frechet contraction):
//   T_l = Z^l; R_l[b] = sum_j T_j[b][0]/(j+l+1)!
//   Q[p,a,b] = sum_l T_l[p,a] R_l[b]
//   dpsi_p[k] = -i sum_a phi_k(a) Q[p,a,a^m_k];  g = 2Re(conj(psi)dpsi)
// ---------------------------------------------------------------------------
__global__ __launch_bounds__(256) void fi_all(
    const void* __restrict__ xv,
    const void* __restrict__ kv,
    const void* __restrict__ bv,
    float* __restrict__ out, int Bn)
{
  const int wg   = blockIdx.x;
  const int i    = wg >> 1;
  const int jblk = wg & 1;             // owns j = 2*jblk, 2*jblk+1
  const int t    = threadIdx.x;        // 0..255
  const int wv   = t >> 6;             // wave id 0..3
  const int tl   = t & 63;             // lane within wave
  const int swv  = ((i & 1) << 1) | jblk;   // solver wave id (SIMD spread)
  const bool solver = (wv == swv);

  __shared__ float  pw[64];
  __shared__ float2 Zl[8][8];
  __shared__ float  invfact[48];
  __shared__ float2 Tall[NTERM * TMAT];
  __shared__ float2 Rl[NTERM][8];
  __shared__ float2 Ql[8][8][8];
  __shared__ float  ampre[8], ampim[8], invPs[8];
  __shared__ __align__(16) float gk_km[64][8];  // g, k-major rows (b128-readable)
  __shared__ __align__(16) float hk_t[8][68];   // h = g/P, p-major, padded

  // ---- wave-parallel dtype sniff: lane tl checks word tl ------------------
  const bool isdbl =
      (__ballot(!(fabsf(((const float*)xv)[tl]) < 1e6f)) != 0ull);

  // ---- phase 1: pw (solver wave) | 1/n! table (next wave, fast rcp) -------
  if (solver) {
    float acc = (float)rdin(bv, tl, isdbl);
    #pragma unroll
    for (int j = 0; j < 4; ++j)
      acc += (float)rdin(xv, i*4 + j, isdbl) * (float)rdin(kv, j*64 + tl, isdbl);
    pw[tl] = acc;
  } else if (wv == ((swv + 1) & 3) && tl < 48) {
    int n = tl;
    float f = 1.0f;
    for (int u = 2; u <= n; ++u) f *= __builtin_amdgcn_rcpf((float)u);
    invfact[n] = f;
  }
  __syncthreads();

  // ---- phase 2: build Z = -iH from analytic Pauli strings (solver wave) ---
  if (solver) {
    int r = tl >> 3, c = tl & 7;
    int m = r ^ c;
    float hre = 0.0f, him = 0.0f;
    for (int u = 0; u < 8; ++u) {
      int k = 0;
      float pr = 1.0f, pim = 0.0f;
      #pragma unroll
      for (int q = 0; q < 3; ++q) {
        int bit = 2 - q;
        int f  = (m >> bit) & 1;
        int ch = (u >> bit) & 1;
        int rb = (r >> bit) & 1;
        int d  = f ? (ch ? 2 : 1) : (ch ? 3 : 0);  // I=0,X=1,Y=2,Z=3
        k = (k << 2) | d;
        if (d == 2) {
          float nr = rb ? -pim : pim;
          float ni = rb ?  pr  : -pr;
          pr = nr; pim = ni;
        } else if (d == 3 && rb) { pr = -pr; pim = -pim; }
      }
      float w = pw[k];
      hre += w * pr; him += w * pim;
    }
    Zl[r][c] = make_float2(him, -hre);   // -i*(hre + i*him)
  }
  __syncthreads();

  // ---- phase 3: Krylov chain T_j = Z^j, register-resident (solver wave) ---
  if (solver) {
    const int r = tl >> 3, c = tl & 7;
    float2 Zrow[8];
    #pragma unroll
    for (int u = 0; u < 8; ++u) Zrow[u] = Zl[r][u];
    float Tre = (r == c) ? 1.0f : 0.0f;
    float Tim = 0.0f;
    Tall[r*TROW + c] = make_float2(Tre, Tim);
    #pragma unroll
    for (int j = 1; j < NTERM; ++j) {
      float cr[8], ci[8];
      #pragma unroll
      for (int u = 0; u < 8; ++u) {
        int srcl = (((u << 3) | c) << 2);            // byte addr = lane*4
        cr[u] = __int_as_float(__builtin_amdgcn_ds_bpermute(srcl, __float_as_int(Tre)));
        ci[u] = __int_as_float(__builtin_amdgcn_ds_bpermute(srcl, __float_as_int(Tim)));
      }
      float nr = 0.0f, ni = 0.0f;
      #pragma unroll
      for (int u = 0; u < 8; ++u) {
        nr += Zrow[u].x*cr[u] - Zrow[u].y*ci[u];
        ni += Zrow[u].x*ci[u] + Zrow[u].y*cr[u];
      }
      Tre = nr; Tim = ni;
      Tall[j*TMAT + r*TROW + c] = make_float2(nr, ni);
    }
  }
  __syncthreads();

  // ---- phase 4: R_l[b] = sum_j A_j[b]/(j+l+1)!  and  psi, 1/P -------------
  if (t < NTERM * 8) {
    const int l = t >> 3, b = t & 7;
    float sr = 0.0f, si = 0.0f;
    for (int j = 0; j < NTERM; ++j) {
      float cf = invfact[j + l + 1];
      float2 a = Tall[j*TMAT + b*TROW];          // A_j[b] = T_j[b][0]
      sr += cf * a.x; si += cf * a.y;
    }
    Rl[l][b] = make_float2(sr, si);
  }
  if (t >= 192 && t < 200) {                      // psi (tiny, post-barrier)
    const int b = t - 192;
    float ar = 0.0f, ai = 0.0f;
    for (int j = 0; j < NTERM; ++j) {
      float cf = invfact[j];
      float2 a = Tall[j*TMAT + b*TROW];
      ar += cf * a.x; ai += cf * a.y;
    }
    ampre[b] = ar; ampim[b] = ai;
    float P = ar*ar + ai*ai;
    invPs[b] = 1.0f / fmaxf(P, 1e-30f);
  }
  __syncthreads();

  // ---- phase 5: Q[p][a][b] = sum_l T_l[p,a] * R_l[b]  (all 256 threads) ---
  {
    const int p  = t >> 5;
    const int a  = (t >> 2) & 7;
    const int b0 = (t & 3) << 1;                 // even -> 16B-aligned Rl pair
    float q0r = 0.f, q0i = 0.f, q1r = 0.f, q1i = 0.f;
    for (int l = 0; l < NTERM; ++l) {
      float2 T  = Tall[l*TMAT + p*TROW + a];
      f4_t  rp  = *(const f4_t*)&Rl[l][b0];      // {r0.re, r0.im, r1.re, r1.im}
      q0r += T.x*rp.x - T.y*rp.y;  q0i += T.x*rp.y + T.y*rp.x;
      q1r += T.x*rp.z - T.y*rp.w;  q1i += T.x*rp.w + T.y*rp.z;
    }
    Ql[p][a][b0]   = make_float2(q0r, q0i);
    Ql[p][a][b0+1] = make_float2(q1r, q1i);
  }
  __syncthreads();

  // ---- phase 6: Jacobian, all 256 threads (k = t&63, 2 p's per thread) ----
  {
    const int k  = t & 63;
    const int pg = t >> 6;               // p in {2pg, 2pg+1}
    const int p0 = pg << 1, p1 = p0 + 1;
    const int d0 = (k >> 4) & 3, d1 = (k >> 2) & 3, d2 = k & 3;
    const int m = ((((d0 == 1) | (d0 == 2)) ? 1 : 0) << 2)
                | ((((d1 == 1) | (d1 == 2)) ? 1 : 0) << 1)
                |  (((d2 == 1) | (d2 == 2)) ? 1 : 0);
    float S0r = 0.f, S0i = 0.f, S1r = 0.f, S1i = 0.f;
    #pragma unroll
    for (int a = 0; a < 8; ++a) {
      float pr = 1.0f, pim = 0.0f;               // phi_k(a) in {+-1, +-i}
      const int dd[3] = {d0, d1, d2};
      #pragma unroll
      for (int q = 0; q < 3; ++q) {
        int rb = (a >> (2 - q)) & 1;
        int d = dd[q];
        if (d == 2) {
          float nr = rb ? -pim : pim;
          float ni = rb ?  pr  : -pr;
          pr = nr; pim = ni;
        } else if (d == 3 && rb) { pr = -pr; pim = -pim; }
      }
      const int b = a ^ m;
      float2 qa = Ql[p0][a][b];
      float2 qb = Ql[p1][a][b];
      S0r += pr*qa.x - pim*qa.y;  S0i += pr*qa.y + pim*qa.x;
      S1r += pr*qb.x - pim*qb.y;  S1i += pr*qb.y + pim*qb.x;
    }
    // dpsi = -i*S ;  g = 2 Re(conj(psi)*dpsi) = 2(psi_re*Si - psi_im*Sr)
    float g0 = 2.0f * (ampre[p0]*S0i - ampim[p0]*S0r);
    float g1 = 2.0f * (ampre[p1]*S1i - ampim[p1]*S1r);
    *(float2*)&gk_km[k][p0] = make_float2(g0, g1);   // k-major row
    hk_t[p0][k] = g0 * invPs[p0];
    hk_t[p1][k] = g1 * invPs[p1];
  }

  // per-thread scales x[2*jblk + jj] * x[l] (l = tl>>4), loaded pre-barrier
  float sc0, sc1;
  {
    float xl = (float)rdin(xv, i*4 + (tl >> 4), isdbl);
    sc0 = xl * (float)rdin(xv, i*4 + 2*jblk,     isdbl);
    sc1 = xl * (float)rdin(xv, i*4 + 2*jblk + 1, isdbl);
  }
  __syncthreads();

  // ---- phase 7: contiguous-1KB-per-wave-instruction stores ----------------
  // hoisted h fragments: column block (tl&15)*4, fixed per thread
  const int m4 = (tl & 15) << 2;
  f4_t hv[8];
  #pragma unroll
  for (int p = 0; p < 8; ++p) hv[p] = *(const f4_t*)&hk_t[p][m4];

  // I_k: two j-slices; wave-uniform row k = (it&15)*4 + wv, jj = it>>4.
  // Lane tl writes floats 4tl..4tl+3 of the contiguous 256-float run.
  {
    float* okj = out + (size_t)i * 65536 + (size_t)(2*jblk) * 16384;
    #pragma unroll
    for (int it = 0; it < 32; ++it) {
      const int jj = it >> 4;
      const int k  = (it & 15)*4 + wv;
      const f4_t ga = *(const f4_t*)&gk_km[k][0];
      const f4_t gb = *(const f4_t*)&gk_km[k][4];
      f4_t acc = ga.x*hv[0] + ga.y*hv[1] + ga.z*hv[2] + ga.w*hv[3]
               + gb.x*hv[4] + gb.y*hv[5] + gb.z*hv[6] + gb.w*hv[7];
      f4_t vv = (jj ? sc1 : sc0) * acc;
      *(f4_t*)(okj + (size_t)jj*16384 + (size_t)k*256 + (size_t)tl*4) = vv;
    }
  }

  // I_b (jblk==0 only): addr = r*1024 + 4t -> contiguous 1KB per wave-instr
  if (jblk == 0) {
    float* ob = out + (size_t)Bn * 65536 + (size_t)i * 4096;
    #pragma unroll
    for (int r = 0; r < 4; ++r) {
      const int k = r*16 + (t >> 4);     // (t>>4)*64 + (t&15)*4 == 4t
      const f4_t ga = *(const f4_t*)&gk_km[k][0];
      const f4_t gb = *(const f4_t*)&gk_km[k][4];
      f4_t acc = ga.x*hv[0] + ga.y*hv[1] + ga.z*hv[2] + ga.w*hv[3]
               + gb.x*hv[4] + gb.y*hv[5] + gb.z*hv[6] + gb.w*hv[7];
      *(f4_t*)(ob + (size_t)r*1024 + (size_t)t*4) = acc;
    }
  }
}

extern "C" void kernel_launch(void* const* d_in, const int* in_sizes, int n_in,
                              void* d_out, int out_size, void* d_ws, size_t ws_size,
                              hipStream_t stream) {
  (void)n_in; (void)d_ws; (void)ws_size; (void)out_size;
  int Bn = in_sizes[0] / 4;   // 256
  fi_all<<<Bn * 2, 256, 0, stream>>>(d_in[0], d_in[1], d_in[2], (float*)d_out, Bn);
}

// Round 11
// 93.060 us; speedup vs baseline: 1.0484x; 1.0115x over previous
//
#include <hip/hip_runtime.h>
#include <math.h>

typedef float f4_t __attribute__((ext_vector_type(4)));

#define NTERM 20           // Taylor powers T_0..T_19 of Z=-iH (||Z||<=4 -> err ~5e-7)
#define TROW  9            // padded row stride (float2) inside one T matrix
#define TMAT  (TROW * 8)   // float2 per stored matrix

__device__ __forceinline__ double rdin(const void* p, int idx, bool isdbl) {
  return isdbl ? ((const double*)p)[idx] : (double)((const float*)p)[idx];
}

// ---------------------------------------------------------------------------
// Single fused kernel. Grid = B workgroups x 256 threads; wg i owns ALL of
// sample i's output: I_k (256 KB) + I_b (16 KB).  1 wg/CU.
//
// R10->R11: final dedup step.  Measured: front dedup saves ~2.2us per
// halving (the throughput-bound phases 5-7 prep contend across co-resident
// wgs; the latency-bound Krylov chain doesn't dedup).  R2 re-analysis shows
// 4 waves/CU drain stores at ~5.9 TB/s (R2's 56us = 44us Jacobi front +
// ~12us drain), so 1 wg/CU loses nothing on the drain.  Phase 7 computes
// each M-row acc ONCE and issues 4 scaled j-copies (16 acc, 64 contiguous
// 1KB wave-stores + 4 for I_b).
//
// Solve math unchanged (Taylor/Krylov + exact Frechet contraction):
//   T_l = Z^l; R_l[b] = sum_j T_j[b][0]/(j+l+1)!
//   Q[p,a,b] = sum_l T_l[p,a] R_l[b]
//   dpsi_p[k] = -i sum_a phi_k(a) Q[p,a,a^m_k];  g = 2Re(conj(psi)dpsi)
// ---------------------------------------------------------------------------
__global__ __launch_bounds__(256) void fi_all(
    const void* __restrict__ xv,
    const void* __restrict__ kv,
    const void* __restrict__ bv,
    float* __restrict__ out, int Bn)
{
  const int i    = blockIdx.x;
  const int t    = threadIdx.x;        // 0..255
  const int wv   = t >> 6;             // wave id 0..3
  const int tl   = t & 63;             // lane within wave
  const int swv  = i & 3;              // solver wave id
  const bool solver = (wv == swv);

  __shared__ float  pw[64];
  __shared__ float2 Zl[8][8];
  __shared__ float  invfact[48];
  __shared__ float2 Tall[NTERM * TMAT];
  __shared__ float2 Rl[NTERM][8];
  __shared__ float2 Ql[8][8][8];
  __shared__ float  ampre[8], ampim[8], invPs[8];
  __shared__ __align__(16) float gk_km[64][8];  // g, k-major rows (b128-readable)
  __shared__ __align__(16) float hk_t[8][68];   // h = g/P, p-major, padded

  // ---- wave-parallel dtype sniff: lane tl checks word tl ------------------
  const bool isdbl =
      (__ballot(!(fabsf(((const float*)xv)[tl]) < 1e6f)) != 0ull);

  // ---- phase 1: pw (solver wave) | 1/n! table (next wave, fast rcp) -------
  if (solver) {
    float acc = (float)rdin(bv, tl, isdbl);
    #pragma unroll
    for (int j = 0; j < 4; ++j)
      acc += (float)rdin(xv, i*4 + j, isdbl) * (float)rdin(kv, j*64 + tl, isdbl);
    pw[tl] = acc;
  } else if (wv == ((swv + 1) & 3) && tl < 48) {
    int n = tl;
    float f = 1.0f;
    for (int u = 2; u <= n; ++u) f *= __builtin_amdgcn_rcpf((float)u);
    invfact[n] = f;
  }
  __syncthreads();

  // ---- phase 2: build Z = -iH from analytic Pauli strings (solver wave) ---
  if (solver) {
    int r = tl >> 3, c = tl & 7;
    int m = r ^ c;
    float hre = 0.0f, him = 0.0f;
    for (int u = 0; u < 8; ++u) {
      int k = 0;
      float pr = 1.0f, pim = 0.0f;
      #pragma unroll
      for (int q = 0; q < 3; ++q) {
        int bit = 2 - q;
        int f  = (m >> bit) & 1;
        int ch = (u >> bit) & 1;
        int rb = (r >> bit) & 1;
        int d  = f ? (ch ? 2 : 1) : (ch ? 3 : 0);  // I=0,X=1,Y=2,Z=3
        k = (k << 2) | d;
        if (d == 2) {
          float nr = rb ? -pim : pim;
          float ni = rb ?  pr  : -pr;
          pr = nr; pim = ni;
        } else if (d == 3 && rb) { pr = -pr; pim = -pim; }
      }
      float w = pw[k];
      hre += w * pr; him += w * pim;
    }
    Zl[r][c] = make_float2(him, -hre);   // -i*(hre + i*him)
  }
  __syncthreads();

  // ---- phase 3: Krylov chain T_j = Z^j, register-resident (solver wave) ---
  if (solver) {
    const int r = tl >> 3, c = tl & 7;
    float2 Zrow[8];
    #pragma unroll
    for (int u = 0; u < 8; ++u) Zrow[u] = Zl[r][u];
    float Tre = (r == c) ? 1.0f : 0.0f;
    float Tim = 0.0f;
    Tall[r*TROW + c] = make_float2(Tre, Tim);
    #pragma unroll
    for (int j = 1; j < NTERM; ++j) {
      float cr[8], ci[8];
      #pragma unroll
      for (int u = 0; u < 8; ++u) {
        int srcl = (((u << 3) | c) << 2);            // byte addr = lane*4
        cr[u] = __int_as_float(__builtin_amdgcn_ds_bpermute(srcl, __float_as_int(Tre)));
        ci[u] = __int_as_float(__builtin_amdgcn_ds_bpermute(srcl, __float_as_int(Tim)));
      }
      float nr = 0.0f, ni = 0.0f;
      #pragma unroll
      for (int u = 0; u < 8; ++u) {
        nr += Zrow[u].x*cr[u] - Zrow[u].y*ci[u];
        ni += Zrow[u].x*ci[u] + Zrow[u].y*cr[u];
      }
      Tre = nr; Tim = ni;
      Tall[j*TMAT + r*TROW + c] = make_float2(nr, ni);
    }
  }
  __syncthreads();

  // ---- phase 4: R_l[b] = sum_j A_j[b]/(j+l+1)!  and  psi, 1/P -------------
  if (t < NTERM * 8) {
    const int l = t >> 3, b = t & 7;
    float sr = 0.0f, si = 0.0f;
    for (int j = 0; j < NTERM; ++j) {
      float cf = invfact[j + l + 1];
      float2 a = Tall[j*TMAT + b*TROW];          // A_j[b] = T_j[b][0]
      sr += cf * a.x; si += cf * a.y;
    }
    Rl[l][b] = make_float2(sr, si);
  }
  if (t >= 192 && t < 200) {                      // psi (tiny, post-barrier)
    const int b = t - 192;
    float ar = 0.0f, ai = 0.0f;
    for (int j = 0; j < NTERM; ++j) {
      float cf = invfact[j];
      float2 a = Tall[j*TMAT + b*TROW];
      ar += cf * a.x; ai += cf * a.y;
    }
    ampre[b] = ar; ampim[b] = ai;
    float P = ar*ar + ai*ai;
    invPs[b] = 1.0f / fmaxf(P, 1e-30f);
  }
  __syncthreads();

  // ---- phase 5: Q[p][a][b] = sum_l T_l[p,a] * R_l[b]  (all 256 threads) ---
  {
    const int p  = t >> 5;
    const int a  = (t >> 2) & 7;
    const int b0 = (t & 3) << 1;                 // even -> 16B-aligned Rl pair
    float q0r = 0.f, q0i = 0.f, q1r = 0.f, q1i = 0.f;
    for (int l = 0; l < NTERM; ++l) {
      float2 T  = Tall[l*TMAT + p*TROW + a];
      f4_t  rp  = *(const f4_t*)&Rl[l][b0];      // {r0.re, r0.im, r1.re, r1.im}
      q0r += T.x*rp.x - T.y*rp.y;  q0i += T.x*rp.y + T.y*rp.x;
      q1r += T.x*rp.z - T.y*rp.w;  q1i += T.x*rp.w + T.y*rp.z;
    }
    Ql[p][a][b0]   = make_float2(q0r, q0i);
    Ql[p][a][b0+1] = make_float2(q1r, q1i);
  }
  __syncthreads();

  // ---- phase 6: Jacobian, all 256 threads (k = t&63, 2 p's per thread) ----
  {
    const int k  = t & 63;
    const int pg = t >> 6;               // p in {2pg, 2pg+1}
    const int p0 = pg << 1, p1 = p0 + 1;
    const int d0 = (k >> 4) & 3, d1 = (k >> 2) & 3, d2 = k & 3;
    const int m = ((((d0 == 1) | (d0 == 2)) ? 1 : 0) << 2)
                | ((((d1 == 1) | (d1 == 2)) ? 1 : 0) << 1)
                |  (((d2 == 1) | (d2 == 2)) ? 1 : 0);
    float S0r = 0.f, S0i = 0.f, S1r = 0.f, S1i = 0.f;
    #pragma unroll
    for (int a = 0; a < 8; ++a) {
      float pr = 1.0f, pim = 0.0f;               // phi_k(a) in {+-1, +-i}
      const int dd[3] = {d0, d1, d2};
      #pragma unroll
      for (int q = 0; q < 3; ++q) {
        int rb = (a >> (2 - q)) & 1;
        int d = dd[q];
        if (d == 2) {
          float nr = rb ? -pim : pim;
          float ni = rb ?  pr  : -pr;
          pr = nr; pim = ni;
        } else if (d == 3 && rb) { pr = -pr; pim = -pim; }
      }
      const int b = a ^ m;
      float2 qa = Ql[p0][a][b];
      float2 qb = Ql[p1][a][b];
      S0r += pr*qa.x - pim*qa.y;  S0i += pr*qa.y + pim*qa.x;
      S1r += pr*qb.x - pim*qb.y;  S1i += pr*qb.y + pim*qb.x;
    }
    // dpsi = -i*S ;  g = 2 Re(conj(psi)*dpsi) = 2(psi_re*Si - psi_im*Sr)
    float g0 = 2.0f * (ampre[p0]*S0i - ampim[p0]*S0r);
    float g1 = 2.0f * (ampre[p1]*S1i - ampim[p1]*S1r);
    *(float2*)&gk_km[k][p0] = make_float2(g0, g1);   // k-major row
    hk_t[p0][k] = g0 * invPs[p0];
    hk_t[p1][k] = g1 * invPs[p1];
  }

  // per-thread scales x[jj]*x[l] (l = tl>>4), loaded before the barrier
  float sc[4];
  {
    float xl = (float)rdin(xv, i*4 + (tl >> 4), isdbl);
    #pragma unroll
    for (int jj = 0; jj < 4; ++jj)
      sc[jj] = xl * (float)rdin(xv, i*4 + jj, isdbl);
  }
  __syncthreads();

  // ---- phase 7: contiguous-1KB-per-wave-instruction stores ----------------
  // hoisted h fragments: column block (tl&15)*4, fixed per thread
  const int m4 = (tl & 15) << 2;
  f4_t hv[8];
  #pragma unroll
  for (int p = 0; p < 8; ++p) hv[p] = *(const f4_t*)&hk_t[p][m4];

  // I_k: wave-uniform row k = it*4 + wv; acc computed ONCE per k, 4 scaled
  // j-copies issued from it.  Lane tl writes floats 4tl..4tl+3 of each
  // contiguous 256-float run I_k[i, jj, k, :, :].
  {
    float* ok = out + (size_t)i * 65536;
    #pragma unroll
    for (int it = 0; it < 16; ++it) {
      const int k = it*4 + wv;
      const f4_t ga = *(const f4_t*)&gk_km[k][0];
      const f4_t gb = *(const f4_t*)&gk_km[k][4];
      f4_t acc = ga.x*hv[0] + ga.y*hv[1] + ga.z*hv[2] + ga.w*hv[3]
               + gb.x*hv[4] + gb.y*hv[5] + gb.z*hv[6] + gb.w*hv[7];
      #pragma unroll
      for (int jj = 0; jj < 4; ++jj) {
        f4_t vv = sc[jj] * acc;
        *(f4_t*)(ok + (size_t)jj*16384 + (size_t)k*256 + (size_t)tl*4) = vv;
      }
    }
  }

  // I_b: addr = r*1024 + 4t -> contiguous 1KB per wave-instruction
  {
    float* ob = out + (size_t)Bn * 65536 + (size_t)i * 4096;
    #pragma unroll
    for (int r = 0; r < 4; ++r) {
      const int k = r*16 + (t >> 4);     // (t>>4)*64 + (t&15)*4 == 4t
      const f4_t ga = *(const f4_t*)&gk_km[k][0];
      const f4_t gb = *(const f4_t*)&gk_km[k][4];
      f4_t acc = ga.x*hv[0] + ga.y*hv[1] + ga.z*hv[2] + ga.w*hv[3]
               + gb.x*hv[4] + gb.y*hv[5] + gb.z*hv[6] + gb.w*hv[7];
      *(f4_t*)(ob + (size_t)r*1024 + (size_t)t*4) = acc;
    }
  }
}

extern "C" void kernel_launch(void* const* d_in, const int* in_sizes, int n_in,
                              void* d_out, int out_size, void* d_ws, size_t ws_size,
                              hipStream_t stream) {
  (void)n_in; (void)d_ws; (void)ws_size; (void)out_size;
  int Bn = in_sizes[0] / 4;   // 256
  fi_all<<<Bn, 256, 0, stream>>>(d_in[0], d_in[1], d_in[2], (float*)d_out, Bn);
}

// Round 12
// 90.540 us; speedup vs baseline: 1.0776x; 1.0278x over previous
//
#include <hip/hip_runtime.h>
#include <math.h>

typedef float f4_t __attribute__((ext_vector_type(4)));

#define NTERM 20           // Taylor powers T_0..T_19 of Z=-iH (||Z||<=4 -> err ~5e-7)
#define TROW  9            // padded row stride (float2) inside one T matrix
#define TMAT  (TROW * 8)   // float2 per stored matrix

// 1/n! table, compile-time (fp32; n>=34 underflows to 0 exactly as the old
// runtime rcp-chain did).  Max index used: (NTERM-1)+(NTERM-1)+1 = 39.
__device__ const float INVFACT[48] = {
  1.0f, 1.0f, 5.0e-1f, 1.66666666666667e-1f, 4.16666666666667e-2f,
  8.33333333333333e-3f, 1.38888888888889e-3f, 1.98412698412698e-4f,
  2.48015873015873e-5f, 2.75573192239859e-6f, 2.75573192239859e-7f,
  2.50521083854417e-8f, 2.08767569878681e-9f, 1.60590438368216e-10f,
  1.14707455977297e-11f, 7.64716373181982e-13f, 4.77947733238738e-14f,
  2.81145725434552e-15f, 1.56192069685862e-16f, 8.22063524662433e-18f,
  4.11031762331216e-19f, 1.95729410633913e-20f, 8.89679139245057e-22f,
  3.86817017063068e-23f, 1.61173757109612e-24f, 6.44695028438447e-26f,
  2.47959626322480e-27f, 9.18368986379555e-29f, 3.27988923706984e-30f,
  1.13099628864477e-31f, 3.76998762881591e-33f, 1.21612504155352e-34f,
  3.80039075485474e-36f, 1.15163356207720e-37f, 3.38715753552116e-39f,
  0.f, 0.f, 0.f, 0.f, 0.f, 0.f, 0.f, 0.f, 0.f, 0.f, 0.f, 0.f, 0.f
};

__device__ __forceinline__ double rdin(const void* p, int idx, bool isdbl) {
  return isdbl ? ((const double*)p)[idx] : (double)((const float*)p)[idx];
}

__device__ __forceinline__ float bpf(int srcl, float v) {
  return __int_as_float(__builtin_amdgcn_ds_bpermute(srcl, __float_as_int(v)));
}

// C = A*B, 8x8 complex, lane-distributed (lane r*8+c holds element [r][c]).
__device__ __forceinline__ void gmul(float& Cr, float& Ci,
                                     float Ar, float Ai, float Br, float Bi,
                                     int r, int c) {
  float nr = 0.f, ni = 0.f;
  #pragma unroll
  for (int u = 0; u < 8; ++u) {
    int sa = ((r << 3) | u) << 2;
    int sb = ((u << 3) | c) << 2;
    float ar = bpf(sa, Ar), ai = bpf(sa, Ai);
    float br = bpf(sb, Br), bi = bpf(sb, Bi);
    nr += ar*br - ai*bi;
    ni += ar*bi + ai*br;
  }
  Cr = nr; Ci = ni;
}

// C = Z*B with Z's row cached in registers (Zrow[u] = Z[r][u]).
__device__ __forceinline__ void zmul(float& Cr, float& Ci,
                                     float Br, float Bi,
                                     const float2* Zrow, int c) {
  float nr = 0.f, ni = 0.f;
  #pragma unroll
  for (int u = 0; u < 8; ++u) {
    int sb = ((u << 3) | c) << 2;
    float br = bpf(sb, Br), bi = bpf(sb, Bi);
    nr += Zrow[u].x*br - Zrow[u].y*bi;
    ni += Zrow[u].x*bi + Zrow[u].y*br;
  }
  Cr = nr; Ci = ni;
}

// ---------------------------------------------------------------------------
// Single fused kernel. Grid = B workgroups x 256 threads; wg i owns ALL of
// sample i's output: I_k (256 KB) + I_b (16 KB).  1 wg/CU.
//
// R11->R12: compress the exposed front (last addressable term; drain is
// floor-bound, dedup exhausted).  (1) phases 1-2 are now WAVE-LOCAL: every
// wave builds pw in registers (lane k holds pw_k) and its own Z via
// bpermute gathers -- no LDS, 2 fewer barriers, no solver-wave serial
// section.  (2) prefix-parallel Krylov: powers 5w..5w+4 per wave; base
// Z^(5w) by repeated squaring (general lane-distributed matmul), then 4
// local left-multiplies -> critical path 9 dependent matmuls vs 19, all 4
// SIMDs busy.  (3) 1/n! is a compile-time constant table.  Barriers 7->4.
// Phases 4-7 unchanged.
// ---------------------------------------------------------------------------
__global__ __launch_bounds__(256) void fi_all(
    const void* __restrict__ xv,
    const void* __restrict__ kv,
    const void* __restrict__ bv,
    float* __restrict__ out, int Bn)
{
  const int i    = blockIdx.x;
  const int t    = threadIdx.x;        // 0..255
  const int wv   = t >> 6;             // wave id 0..3
  const int tl   = t & 63;             // lane within wave

  __shared__ float2 Tall[NTERM * TMAT];
  __shared__ float2 Rl[NTERM][8];
  __shared__ float2 Ql[8][8][8];
  __shared__ float  ampre[8], ampim[8], invPs[8];
  __shared__ __align__(16) float gk_km[64][8];  // g, k-major rows (b128-readable)
  __shared__ __align__(16) float hk_t[8][68];   // h = g/P, p-major, padded

  // ---- wave-parallel dtype sniff: lane tl checks word tl ------------------
  const bool isdbl =
      (__ballot(!(fabsf(((const float*)xv)[tl]) < 1e6f)) != 0ull);

  // ---- phases 1-3, wave-local (all 4 waves, no barriers) ------------------
  // pw in registers: lane k (=tl) holds pw_k
  float pwv = (float)rdin(bv, tl, isdbl);
  #pragma unroll
  for (int j = 0; j < 4; ++j)
    pwv += (float)rdin(xv, i*4 + j, isdbl) * (float)rdin(kv, j*64 + tl, isdbl);

  // Z = -iH from analytic Pauli strings, pw gathered via bpermute
  const int r = tl >> 3, c = tl & 7;
  float Zre, Zim;
  {
    int m = r ^ c;
    float hre = 0.f, him = 0.f;
    #pragma unroll
    for (int u = 0; u < 8; ++u) {
      int k = 0; float pr = 1.f, pim = 0.f;
      #pragma unroll
      for (int q = 0; q < 3; ++q) {
        int bit = 2 - q;
        int f  = (m >> bit) & 1;
        int ch = (u >> bit) & 1;
        int rb = (r >> bit) & 1;
        int d  = f ? (ch ? 2 : 1) : (ch ? 3 : 0);  // I=0,X=1,Y=2,Z=3
        k = (k << 2) | d;
        if (d == 2) {
          float nr = rb ? -pim : pim;
          float ni = rb ?  pr  : -pr;
          pr = nr; pim = ni;
        } else if (d == 3 && rb) { pr = -pr; pim = -pim; }
      }
      float w = bpf(k << 2, pwv);
      hre += w * pr; him += w * pim;
    }
    Zre = him; Zim = -hre;               // -i*(hre + i*him)
  }

  // Z row cache: Zrow[u] = Z[r][u]
  float2 Zrow[8];
  #pragma unroll
  for (int u = 0; u < 8; ++u) {
    int s = ((r << 3) | u) << 2;
    Zrow[u] = make_float2(bpf(s, Zre), bpf(s, Zim));
  }

  // prefix-parallel powers: wave w produces T_{5w}..T_{5w+4}
  float Z2r, Z2i; zmul(Z2r, Z2i, Zre, Zim, Zrow, c);   // Z^2 (all waves)
  if (wv == 0) {
    Tall[0*TMAT + r*TROW + c] = make_float2((r == c) ? 1.f : 0.f, 0.f);
    Tall[1*TMAT + r*TROW + c] = make_float2(Zre, Zim);
    Tall[2*TMAT + r*TROW + c] = make_float2(Z2r, Z2i);
    float cr_ = Z2r, ci_ = Z2i;
    #pragma unroll
    for (int s = 3; s < 5; ++s) {
      float nr_, ni_; zmul(nr_, ni_, cr_, ci_, Zrow, c);
      cr_ = nr_; ci_ = ni_;
      Tall[s*TMAT + r*TROW + c] = make_float2(cr_, ci_);
    }
  } else {
    float Z4r, Z4i; gmul(Z4r, Z4i, Z2r, Z2i, Z2r, Z2i, r, c);   // Z^4
    float Z5r, Z5i; zmul(Z5r, Z5i, Z4r, Z4i, Zrow, c);          // Z^5
    float Cr_, Ci_;
    if (wv == 1) { Cr_ = Z5r; Ci_ = Z5i; }
    else {
      float Z10r, Z10i; gmul(Z10r, Z10i, Z5r, Z5i, Z5r, Z5i, r, c);  // Z^10
      if (wv == 2) { Cr_ = Z10r; Ci_ = Z10i; }
      else         { gmul(Cr_, Ci_, Z10r, Z10i, Z5r, Z5i, r, c); }   // Z^15
    }
    const int base = wv * 5;
    Tall[base*TMAT + r*TROW + c] = make_float2(Cr_, Ci_);
    #pragma unroll
    for (int s = 1; s < 5; ++s) {
      float nr_, ni_; zmul(nr_, ni_, Cr_, Ci_, Zrow, c);
      Cr_ = nr_; Ci_ = ni_;
      Tall[(base + s)*TMAT + r*TROW + c] = make_float2(Cr_, Ci_);
    }
  }
  __syncthreads();

  // ---- phase 4: R_l[b] = sum_j A_j[b]/(j+l+1)!  and  psi, 1/P -------------
  if (t < NTERM * 8) {
    const int l = t >> 3, b = t & 7;
    float sr = 0.0f, si = 0.0f;
    #pragma unroll
    for (int j = 0; j < NTERM; ++j) {
      float cf = INVFACT[j + l + 1];
      float2 a = Tall[j*TMAT + b*TROW];          // A_j[b] = T_j[b][0]
      sr += cf * a.x; si += cf * a.y;
    }
    Rl[l][b] = make_float2(sr, si);
  }
  if (t >= 192 && t < 200) {                      // psi
    const int b = t - 192;
    float ar = 0.0f, ai = 0.0f;
    #pragma unroll
    for (int j = 0; j < NTERM; ++j) {
      float cf = INVFACT[j];
      float2 a = Tall[j*TMAT + b*TROW];
      ar += cf * a.x; ai += cf * a.y;
    }
    ampre[b] = ar; ampim[b] = ai;
    float P = ar*ar + ai*ai;
    invPs[b] = 1.0f / fmaxf(P, 1e-30f);
  }
  __syncthreads();

  // ---- phase 5: Q[p][a][b] = sum_l T_l[p,a] * R_l[b]  (all 256 threads) ---
  {
    const int p  = t >> 5;
    const int a  = (t >> 2) & 7;
    const int b0 = (t & 3) << 1;                 // even -> 16B-aligned Rl pair
    float q0r = 0.f, q0i = 0.f, q1r = 0.f, q1i = 0.f;
    #pragma unroll
    for (int l = 0; l < NTERM; ++l) {
      float2 T  = Tall[l*TMAT + p*TROW + a];
      f4_t  rp  = *(const f4_t*)&Rl[l][b0];      // {r0.re, r0.im, r1.re, r1.im}
      q0r += T.x*rp.x - T.y*rp.y;  q0i += T.x*rp.y + T.y*rp.x;
      q1r += T.x*rp.z - T.y*rp.w;  q1i += T.x*rp.w + T.y*rp.z;
    }
    Ql[p][a][b0]   = make_float2(q0r, q0i);
    Ql[p][a][b0+1] = make_float2(q1r, q1i);
  }
  __syncthreads();

  // ---- phase 6: Jacobian, all 256 threads (k = t&63, 2 p's per thread) ----
  {
    const int k  = t & 63;
    const int pg = t >> 6;               // p in {2pg, 2pg+1}
    const int p0 = pg << 1, p1 = p0 + 1;
    const int d0 = (k >> 4) & 3, d1 = (k >> 2) & 3, d2 = k & 3;
    const int m = ((((d0 == 1) | (d0 == 2)) ? 1 : 0) << 2)
                | ((((d1 == 1) | (d1 == 2)) ? 1 : 0) << 1)
                |  (((d2 == 1) | (d2 == 2)) ? 1 : 0);
    float S0r = 0.f, S0i = 0.f, S1r = 0.f, S1i = 0.f;
    #pragma unroll
    for (int a = 0; a < 8; ++a) {
      float pr = 1.0f, pim = 0.0f;               // phi_k(a) in {+-1, +-i}
      const int dd[3] = {d0, d1, d2};
      #pragma unroll
      for (int q = 0; q < 3; ++q) {
        int rb = (a >> (2 - q)) & 1;
        int d = dd[q];
        if (d == 2) {
          float nr = rb ? -pim : pim;
          float ni = rb ?  pr  : -pr;
          pr = nr; pim = ni;
        } else if (d == 3 && rb) { pr = -pr; pim = -pim; }
      }
      const int b = a ^ m;
      float2 qa = Ql[p0][a][b];
      float2 qb = Ql[p1][a][b];
      S0r += pr*qa.x - pim*qa.y;  S0i += pr*qa.y + pim*qa.x;
      S1r += pr*qb.x - pim*qb.y;  S1i += pr*qb.y + pim*qb.x;
    }
    // dpsi = -i*S ;  g = 2 Re(conj(psi)*dpsi) = 2(psi_re*Si - psi_im*Sr)
    float g0 = 2.0f * (ampre[p0]*S0i - ampim[p0]*S0r);
    float g1 = 2.0f * (ampre[p1]*S1i - ampim[p1]*S1r);
    *(float2*)&gk_km[k][p0] = make_float2(g0, g1);   // k-major row
    hk_t[p0][k] = g0 * invPs[p0];
    hk_t[p1][k] = g1 * invPs[p1];
  }

  // per-thread scales x[jj]*x[l] (l = tl>>4), loaded before the barrier
  float sc[4];
  {
    float xl = (float)rdin(xv, i*4 + (tl >> 4), isdbl);
    #pragma unroll
    for (int jj = 0; jj < 4; ++jj)
      sc[jj] = xl * (float)rdin(xv, i*4 + jj, isdbl);
  }
  __syncthreads();

  // ---- phase 7: contiguous-1KB-per-wave-instruction stores ----------------
  // hoisted h fragments: column block (tl&15)*4, fixed per thread
  const int m4 = (tl & 15) << 2;
  f4_t hv[8];
  #pragma unroll
  for (int p = 0; p < 8; ++p) hv[p] = *(const f4_t*)&hk_t[p][m4];

  // I_k: wave-uniform row k = it*4 + wv; acc computed ONCE per k, 4 scaled
  // j-copies issued from it.  Lane tl writes floats 4tl..4tl+3 of each
  // contiguous 256-float run I_k[i, jj, k, :, :].
  {
    float* ok = out + (size_t)i * 65536;
    #pragma unroll
    for (int it = 0; it < 16; ++it) {
      const int k = it*4 + wv;
      const f4_t ga = *(const f4_t*)&gk_km[k][0];
      const f4_t gb = *(const f4_t*)&gk_km[k][4];
      f4_t acc = ga.x*hv[0] + ga.y*hv[1] + ga.z*hv[2] + ga.w*hv[3]
               + gb.x*hv[4] + gb.y*hv[5] + gb.z*hv[6] + gb.w*hv[7];
      #pragma unroll
      for (int jj = 0; jj < 4; ++jj) {
        f4_t vv = sc[jj] * acc;
        *(f4_t*)(ok + (size_t)jj*16384 + (size_t)k*256 + (size_t)tl*4) = vv;
      }
    }
  }

  // I_b: addr = r*1024 + 4t -> contiguous 1KB per wave-instruction
  {
    float* ob = out + (size_t)Bn * 65536 + (size_t)i * 4096;
    #pragma unroll
    for (int rr = 0; rr < 4; ++rr) {
      const int k = rr*16 + (t >> 4);    // (t>>4)*64 + (t&15)*4 == 4t
      const f4_t ga = *(const f4_t*)&gk_km[k][0];
      const f4_t gb = *(const f4_t*)&gk_km[k][4];
      f4_t acc = ga.x*hv[0] + ga.y*hv[1] + ga.z*hv[2] + ga.w*hv[3]
               + gb.x*hv[4] + gb.y*hv[5] + gb.z*hv[6] + gb.w*hv[7];
      *(f4_t*)(ob + (size_t)rr*1024 + (size_t)t*4) = acc;
    }
  }
}

extern "C" void kernel_launch(void* const* d_in, const int* in_sizes, int n_in,
                              void* d_out, int out_size, void* d_ws, size_t ws_size,
                              hipStream_t stream) {
  (void)n_in; (void)d_ws; (void)ws_size; (void)out_size;
  int Bn = in_sizes[0] / 4;   // 256
  fi_all<<<Bn, 256, 0, stream>>>(d_in[0], d_in[1], d_in[2], (float*)d_out, Bn);
}